// Round 2
// baseline (479.414 us; speedup 1.0000x reference)
//
#include <hip/hip_runtime.h>
#include <hip/hip_bf16.h>

typedef __bf16 bf16x8 __attribute__((ext_vector_type(8)));
typedef __bf16 bf16x4 __attribute__((ext_vector_type(4)));
typedef float  f32x4  __attribute__((ext_vector_type(4)));

// ---------------------------------------------------------------------------
// Kernel 1: prep (unchanged — validated)
// ---------------------------------------------------------------------------
__global__ __launch_bounds__(256) void prep_kernel(
    const float* __restrict__ img, const float* __restrict__ ques,
    const float* __restrict__ g_w1, const float* __restrict__ g_b1,
    const float* __restrict__ g_w2, const float* __restrict__ g_w3,
    const float* __restrict__ g_w4,
    float* __restrict__ U, float* __restrict__ V, float* __restrict__ Qb,
    __bf16* __restrict__ W2t, __bf16* __restrict__ W3t, __bf16* __restrict__ W4t) {
  __shared__ float smem[64 * 65];
  const int blk = blockIdx.x;
  const int t = threadIdx.x;

  if (blk < 256) {
    const int n = blk >> 2, obase = (blk & 3) * 16;
    for (int idx = t; idx < 66 * 16; idx += 256) {
      const int c = idx >> 4, o = obase + (idx & 15);
      float v;
      if (c < 64)      v = img[n * 4096 + c * 64 + o];
      else if (c == 64) v = (float)(o >> 3);
      else              v = (float)(o & 7);
      smem[idx] = v;
    }
    __syncthreads();
    float u[16], vv[16];
#pragma unroll
    for (int o = 0; o < 16; ++o) { u[o] = 0.f; vv[o] = 0.f; }
    for (int d = 0; d < 66; ++d) {
      const float wu = g_w1[d * 256 + t];
      const float wv = g_w1[(66 + d) * 256 + t];
#pragma unroll
      for (int o = 0; o < 16; ++o) {
        const float cc = smem[d * 16 + o];
        u[o]  += cc * wu;
        vv[o] += cc * wv;
      }
    }
#pragma unroll
    for (int o = 0; o < 16; ++o) {
      U[(size_t)(n * 64 + obase + o) * 256 + t] = u[o];
      V[(size_t)(n * 64 + obase + o) * 256 + t] = vv[o];
    }
  } else if (blk < 320) {
    const int n = blk - 256;
    smem[t] = ques[n * 256 + t];
    __syncthreads();
    float s = g_b1[t];
    for (int e = 0; e < 256; ++e) s += smem[e] * g_w1[(132 + e) * 256 + t];
    Qb[n * 256 + t] = s;
  } else {
    const int b2 = blk - 320;
    const int wsel = b2 >> 4;
    const int tile = b2 & 15;
    const int r0 = (tile >> 2) * 64, c0 = (tile & 3) * 64;
    const float* W = (wsel == 0) ? g_w2 : (wsel == 1) ? g_w3 : g_w4;
    __bf16* Wt    = (wsel == 0) ? W2t  : (wsel == 1) ? W3t  : W4t;
    const int col = t & 63, rb = (t >> 6) * 16;
#pragma unroll 4
    for (int j = 0; j < 16; ++j)
      smem[(rb + j) * 65 + col] = W[(size_t)(r0 + rb + j) * 256 + c0 + col];
    __syncthreads();
#pragma unroll 4
    for (int j = 0; j < 16; ++j)
      Wt[(size_t)(c0 + rb + j) * 256 + r0 + col] = (__bf16)smem[col * 65 + rb + j];
  }
}

// ---------------------------------------------------------------------------
// Kernel 2: fused g-MLP layers 2..4. 512 thr / 8 waves, one (n,i) per block.
//  ROUND-1 CHANGE: wave decomposition 1x8 -> 2x4.
//   wave (rw = nq>>2, cw = nq&3) owns rows [rw*32,+32) x cols [cw*64,+64).
//   A-fragment LDS reads per wave per layer: 32 -> 16 ds_read_b128
//   (amplification 8x -> 4x of the 32KB H tile). W-loads 2x duplicated but
//   L2-served (3x128KB weights, ~15 TB/s aggregate << 34.5 TB/s ceiling).
//  - depth-2 rolling B-prefetch ring (4 col-tiles/slot), rolls across layers
//  - K-split triple-buffer LDS (3 x 16 KB). Rotation per layer:
//    read (lo=X, hi=Y), write lo->Z, hi->X. BAR1 post-K-loop protects X.
//  Local idx within one 16KB half: elem(row,c) = (c>>3)*512 + ((row+(c>>3))&63)*8 + (c&7)
// ---------------------------------------------------------------------------
#define HB 8192   // bf16 elems per 16 KB K-half buffer

__device__ __forceinline__ int hidx(int row, int c) {
  const int kb = c >> 3;
  return kb * 512 + (((row + kb) & 63) << 3) + (c & 7);
}

template <bool LAST>
__device__ __forceinline__ void g_layer(const __bf16* Rlo, const __bf16* Rhi,
                                        __bf16* Wlo, __bf16* Whi,
                                        bf16x8 ring[2][4],
                                        const __bf16* __restrict__ wcur,
                                        const __bf16* __restrict__ wnext,
                                        const float* __restrict__ bias_g,
                                        int rw, int cw, int q, int r16,
                                        float* __restrict__ part_row,
                                        __bf16* __restrict__ red_base) {
  f32x4 acc[2][4];
  const f32x4 z = {0.f, 0.f, 0.f, 0.f};
#pragma unroll
  for (int m = 0; m < 2; ++m)
#pragma unroll
    for (int nt = 0; nt < 4; ++nt) acc[m][nt] = z;

#pragma unroll
  for (int ks = 0; ks < 8; ++ks) {
    const __bf16* R = (ks < 4) ? Rlo : Rhi;   // compile-time select (full unroll)
    const int kbl = (ks & 3) * 4 + q;         // buffer-local K-chunk
    bf16x8 a[2];
#pragma unroll
    for (int m = 0; m < 2; ++m) {
      const int row = rw * 32 + m * 16 + r16;
      a[m] = *(const bf16x8*)(&R[kbl * 512 + (((row + kbl) & 63) << 3)]);
    }
    bf16x8 b[4];
#pragma unroll
    for (int nt = 0; nt < 4; ++nt) b[nt] = ring[ks & 1][nt];
    // refill slot: 2 iterations ahead (crosses into next layer's W)
    if (ks < 6) {
#pragma unroll
      for (int nt = 0; nt < 4; ++nt)
        ring[ks & 1][nt] = *(const bf16x8*)(wcur + nt * 4096 + (ks + 2) * 32);
    } else if (!LAST) {
#pragma unroll
      for (int nt = 0; nt < 4; ++nt)
        ring[ks & 1][nt] = *(const bf16x8*)(wnext + nt * 4096 + (ks - 6) * 32);
    }
#pragma unroll
    for (int m = 0; m < 2; ++m)
#pragma unroll
      for (int nt = 0; nt < 4; ++nt)
        // swapped operands (verified): acc[m][nt] -> row rw*32+m*16+r16,
        // cols cw*64 + nt*16 + q*4 + reg
        acc[m][nt] = __builtin_amdgcn_mfma_f32_16x16x32_bf16(b[nt], a[m], acc[m][nt], 0, 0, 0);
  }

  f32x4 bv[4];
#pragma unroll
  for (int nt = 0; nt < 4; ++nt)
    bv[nt] = *(const f32x4*)&bias_g[cw * 64 + nt * 16 + q * 4];

  if (!LAST) {
    // compute store values first (register math overlaps barrier wait)
    bf16x4 hv[2][4];
#pragma unroll
    for (int m = 0; m < 2; ++m)
#pragma unroll
      for (int nt = 0; nt < 4; ++nt) {
        const f32x4 s = acc[m][nt] + bv[nt];
        bf16x4 h;
#pragma unroll
        for (int r = 0; r < 4; ++r) h[r] = (__bf16)fmaxf(s[r], 0.f);
        hv[m][nt] = h;
      }
    __syncthreads();   // BAR1: all waves done reading Rlo/Rhi -> X reusable
    __bf16* Wd = (cw < 2) ? Wlo : Whi;
    const int clb = (cw & 1) * 64 + q * 4;    // buffer-local col base
#pragma unroll
    for (int m = 0; m < 2; ++m)
#pragma unroll
      for (int nt = 0; nt < 4; ++nt)
        *(bf16x4*)(&Wd[hidx(rw * 32 + m * 16 + r16, clb + nt * 16)]) = hv[m][nt];
    __syncthreads();   // BAR2: stores visible before next layer's reads
  } else {
    f32x4 s[4];
#pragma unroll
    for (int nt = 0; nt < 4; ++nt) {
#pragma unroll
      for (int r = 0; r < 4; ++r)
        s[nt][r] = fmaxf(acc[0][nt][r] + bv[nt][r], 0.f)
                 + fmaxf(acc[1][nt][r] + bv[nt][r], 0.f);
#pragma unroll
      for (int d = 1; d < 16; d <<= 1) {
#pragma unroll
        for (int r = 0; r < 4; ++r) s[nt][r] += __shfl_xor(s[nt][r], d, 64);
      }
    }
    // cross-wave (rw=1 -> rw=0) combine through free P0 buffer
    float* red = (float*)red_base;
    if (rw == 1 && r16 == 0) {
#pragma unroll
      for (int nt = 0; nt < 4; ++nt)
        *(f32x4*)&red[cw * 64 + nt * 16 + q * 4] = s[nt];
    }
    __syncthreads();
    if (rw == 0) {
#pragma unroll
      for (int nt = 0; nt < 4; ++nt) {
        const f32x4 o = *(const f32x4*)&red[cw * 64 + nt * 16 + q * 4];
        s[nt] += o;
      }
      if (r16 == 0) {
#pragma unroll
        for (int nt = 0; nt < 4; ++nt)
          *(f32x4*)&part_row[cw * 64 + nt * 16 + q * 4] = s[nt];
      }
    }
  }
}

__global__ __launch_bounds__(512, 4) void rn_main(
    const float* __restrict__ U, const float* __restrict__ V,
    const float* __restrict__ Qb,
    const __bf16* __restrict__ W2t, const __bf16* __restrict__ W3t,
    const __bf16* __restrict__ W4t,
    const float* __restrict__ b2, const float* __restrict__ b3,
    const float* __restrict__ b4,
    float* __restrict__ part) {
  __shared__ __align__(16) __bf16 Hs[3 * HB];   // 48 KB
  const int blk = blockIdx.x;
  const int nimg = blk >> 6, iobj = blk & 63;
  const int t = threadIdx.x;
  const int nq = t >> 6, lane = t & 63;
  const int rw = nq >> 2, cw = nq & 3;
  const int q = lane >> 4, r16 = lane & 15;

  // per-wave W base pointers (row = output col = cw*64 + nt*16 + r16, K off q*8)
  const size_t woff = (size_t)(cw * 64 + r16) * 256 + q * 8;
  const __bf16* w2 = W2t + woff;
  const __bf16* w3 = W3t + woff;
  const __bf16* w4 = W4t + woff;

  // start layer-2 B ring fill immediately (overlaps phase-0 loads/math)
  bf16x8 ring[2][4];
#pragma unroll
  for (int d = 0; d < 2; ++d)
#pragma unroll
    for (int nt = 0; nt < 4; ++nt)
      ring[d][nt] = *(const bf16x8*)(w2 + nt * 4096 + d * 32);

  // phase 0: h1[j][:] = relu(U[n,i,:] + V[n,j,:] + Qb[n,:])
  // lo cols (0..127) -> P0 = Hs, hi cols (128..255) -> P1 = Hs+HB
  {
    const int c4 = t & 63;
    const int jb = (t >> 6) * 8;
    const f32x4 u4 = *(const f32x4*)&U[(size_t)(nimg * 64 + iobj) * 256 + c4 * 4];
    const f32x4 q4 = *(const f32x4*)&Qb[(size_t)nimg * 256 + c4 * 4];
    const f32x4 uq = u4 + q4;
    __bf16* Pd = (c4 < 32) ? Hs : (Hs + HB);
    const int cl = (c4 & 31) * 4;   // buffer-local col
#pragma unroll
    for (int jj = 0; jj < 8; ++jj) {
      const int row = jb + jj;
      const f32x4 v4 = *(const f32x4*)&V[(size_t)(nimg * 64 + row) * 256 + c4 * 4];
      bf16x4 h;
#pragma unroll
      for (int r = 0; r < 4; ++r) h[r] = (__bf16)fmaxf(uq[r] + v4[r], 0.f);
      *(bf16x4*)(&Pd[hidx(row, cl)]) = h;
    }
  }
  __syncthreads();

  float* part_row = part + (size_t)blk * 256;

  // rotation: L2 reads (P0,P1) writes lo->P2 hi->P0
  //           L3 reads (P2,P0) writes lo->P1 hi->P2
  //           L4 reads (P1,P2) -> registers; P0 reused as reduce scratch
  g_layer<false>(Hs,          Hs + HB,     Hs + 2 * HB, Hs,          ring, w2, w3, b2, rw, cw, q, r16, part_row, Hs);
  g_layer<false>(Hs + 2 * HB, Hs,          Hs + HB,     Hs + 2 * HB, ring, w3, w4, b3, rw, cw, q, r16, part_row, Hs);
  g_layer<true >(Hs + HB,     Hs + 2 * HB, Hs,          Hs,          ring, w4, w4, b4, rw, cw, q, r16, part_row, Hs);
}

// ---------------------------------------------------------------------------
// Kernel 3: reduce partials -> context, f-MLP (fp32), log_softmax
// ---------------------------------------------------------------------------
__global__ __launch_bounds__(256) void rn_final(
    const float* __restrict__ part,
    const float* __restrict__ f_w1, const float* __restrict__ f_b1,
    const float* __restrict__ f_w2, const float* __restrict__ f_b2,
    const float* __restrict__ f_w3, const float* __restrict__ f_b3,
    float* __restrict__ out) {
  __shared__ float ctx[256], y1[256], y2[256], sc[2];
  const int n = blockIdx.x, t = threadIdx.x;

  float s = 0.f;
  for (int i = 0; i < 64; ++i) s += part[((size_t)n * 64 + i) * 256 + t];
  ctx[t] = s * (1.0f / 4096.0f);
  __syncthreads();

  float a = f_b1[t];
  for (int k = 0; k < 256; ++k) a += ctx[k] * f_w1[k * 256 + t];
  y1[t] = fmaxf(a, 0.f);
  __syncthreads();

  float b = f_b2[t];
  for (int k = 0; k < 256; ++k) b += y1[k] * f_w2[k * 256 + t];
  y2[t] = fmaxf(b, 0.f);
  __syncthreads();

  if (t < 2) {
    float c = f_b3[t];
    for (int k = 0; k < 256; ++k) c += y2[k] * f_w3[k * 2 + t];
    sc[t] = c;
  }
  __syncthreads();

  if (t == 0) {
    const float s0 = sc[0], s1 = sc[1];
    const float mx = fmaxf(s0, s1);
    const float lse = mx + logf(expf(s0 - mx) + expf(s1 - mx));
    out[n * 2 + 0] = s0 - lse;
    out[n * 2 + 1] = s1 - lse;
  }
}

// ---------------------------------------------------------------------------
extern "C" void kernel_launch(void* const* d_in, const int* in_sizes, int n_in,
                              void* d_out, int out_size, void* d_ws, size_t ws_size,
                              hipStream_t stream) {
  const float* img  = (const float*)d_in[0];
  const float* ques = (const float*)d_in[1];
  const float* g_w1 = (const float*)d_in[2];
  const float* g_b1 = (const float*)d_in[3];
  const float* g_w2 = (const float*)d_in[4];
  const float* g_b2 = (const float*)d_in[5];
  const float* g_w3 = (const float*)d_in[6];
  const float* g_b3 = (const float*)d_in[7];
  const float* g_w4 = (const float*)d_in[8];
  const float* g_b4 = (const float*)d_in[9];
  const float* f_w1 = (const float*)d_in[10];
  const float* f_b1 = (const float*)d_in[11];
  const float* f_w2 = (const float*)d_in[12];
  const float* f_b2 = (const float*)d_in[13];
  const float* f_w3 = (const float*)d_in[14];
  const float* f_b3 = (const float*)d_in[15];
  float* out = (float*)d_out;

  char* ws = (char*)d_ws;
  float*  U    = (float*)(ws);                                 // 4 MB
  float*  V    = (float*)(ws + (size_t)4  * 1048576);          // 4 MB
  float*  part = (float*)(ws + (size_t)8  * 1048576);          // 4 MB
  float*  Qb   = (float*)(ws + (size_t)12 * 1048576);          // 64 KB
  __bf16* W2t  = (__bf16*)(ws + (size_t)12 * 1048576 + 65536); // 128 KB each
  __bf16* W3t  = W2t + 65536;
  __bf16* W4t  = W3t + 65536;

  prep_kernel<<<368, 256, 0, stream>>>(img, ques, g_w1, g_b1, g_w2, g_w3, g_w4,
                                       U, V, Qb, W2t, W3t, W4t);
  rn_main<<<4096, 512, 0, stream>>>(U, V, Qb, W2t, W3t, W4t, g_b2, g_b3, g_b4, part);
  rn_final<<<64, 256, 0, stream>>>(part, f_w1, f_b1, f_w2, f_b2, f_w3, f_b3, out);
}

// Round 3
// 250.786 us; speedup vs baseline: 1.9116x; 1.9116x over previous
//
#include <hip/hip_runtime.h>
#include <hip/hip_bf16.h>

typedef __bf16 bf16x8 __attribute__((ext_vector_type(8)));
typedef __bf16 bf16x4 __attribute__((ext_vector_type(4)));
typedef float  f32x4  __attribute__((ext_vector_type(4)));

// ---------------------------------------------------------------------------
// Kernel 1: prep (unchanged — validated)
// ---------------------------------------------------------------------------
__global__ __launch_bounds__(256) void prep_kernel(
    const float* __restrict__ img, const float* __restrict__ ques,
    const float* __restrict__ g_w1, const float* __restrict__ g_b1,
    const float* __restrict__ g_w2, const float* __restrict__ g_w3,
    const float* __restrict__ g_w4,
    float* __restrict__ U, float* __restrict__ V, float* __restrict__ Qb,
    __bf16* __restrict__ W2t, __bf16* __restrict__ W3t, __bf16* __restrict__ W4t) {
  __shared__ float smem[64 * 65];
  const int blk = blockIdx.x;
  const int t = threadIdx.x;

  if (blk < 256) {
    const int n = blk >> 2, obase = (blk & 3) * 16;
    for (int idx = t; idx < 66 * 16; idx += 256) {
      const int c = idx >> 4, o = obase + (idx & 15);
      float v;
      if (c < 64)      v = img[n * 4096 + c * 64 + o];
      else if (c == 64) v = (float)(o >> 3);
      else              v = (float)(o & 7);
      smem[idx] = v;
    }
    __syncthreads();
    float u[16], vv[16];
#pragma unroll
    for (int o = 0; o < 16; ++o) { u[o] = 0.f; vv[o] = 0.f; }
    for (int d = 0; d < 66; ++d) {
      const float wu = g_w1[d * 256 + t];
      const float wv = g_w1[(66 + d) * 256 + t];
#pragma unroll
      for (int o = 0; o < 16; ++o) {
        const float cc = smem[d * 16 + o];
        u[o]  += cc * wu;
        vv[o] += cc * wv;
      }
    }
#pragma unroll
    for (int o = 0; o < 16; ++o) {
      U[(size_t)(n * 64 + obase + o) * 256 + t] = u[o];
      V[(size_t)(n * 64 + obase + o) * 256 + t] = vv[o];
    }
  } else if (blk < 320) {
    const int n = blk - 256;
    smem[t] = ques[n * 256 + t];
    __syncthreads();
    float s = g_b1[t];
    for (int e = 0; e < 256; ++e) s += smem[e] * g_w1[(132 + e) * 256 + t];
    Qb[n * 256 + t] = s;
  } else {
    const int b2 = blk - 320;
    const int wsel = b2 >> 4;
    const int tile = b2 & 15;
    const int r0 = (tile >> 2) * 64, c0 = (tile & 3) * 64;
    const float* W = (wsel == 0) ? g_w2 : (wsel == 1) ? g_w3 : g_w4;
    __bf16* Wt    = (wsel == 0) ? W2t  : (wsel == 1) ? W3t  : W4t;
    const int col = t & 63, rb = (t >> 6) * 16;
#pragma unroll 4
    for (int j = 0; j < 16; ++j)
      smem[(rb + j) * 65 + col] = W[(size_t)(r0 + rb + j) * 256 + c0 + col];
    __syncthreads();
#pragma unroll 4
    for (int j = 0; j < 16; ++j)
      Wt[(size_t)(c0 + rb + j) * 256 + r0 + col] = (__bf16)smem[col * 65 + rb + j];
  }
}

// ---------------------------------------------------------------------------
// Kernel 2: fused g-MLP layers 2..4.
//  ROUND-2: M=128 per block (2 i-objects), 512 thr / 8 waves.
//   - wave nq owns ALL 128 rows x 32-col strip: zero W duplication (round-1
//     lesson), depth-4 W ring (lead = 4 iters ~ 440+ cyc > L2 latency).
//   - 128 MFMA per wave per barrier window (2x round-0) -> fewer convoys.
//   - SINGLE 64 KB in-place H buffer: every wave reads the whole buffer in
//     its K-loop, so BAR1 (post-K-loop, pre-store) makes in-place overwrite
//     safe. BAR2 publishes stores. 2 barriers per non-last layer.
//  H layout: elem(row,c) = (c>>3)*1024 + ((row+(c>>3))&127)*8 + (c&7)
// ---------------------------------------------------------------------------
__device__ __forceinline__ int hidx128(int row, int c) {
  const int kb = c >> 3;
  return kb * 1024 + (((row + kb) & 127) << 3) + (c & 7);
}

template <bool LAST>
__device__ __forceinline__ void g_layer(__bf16* Hs,
                                        bf16x8 ring[4][2],
                                        const __bf16* __restrict__ wcur,
                                        const __bf16* __restrict__ wnext,
                                        const float* __restrict__ bias_g,
                                        int nq, int q, int r16,
                                        float* __restrict__ pr0,
                                        float* __restrict__ pr1) {
  f32x4 acc[8][2];
  const f32x4 z = {0.f, 0.f, 0.f, 0.f};
#pragma unroll
  for (int m = 0; m < 8; ++m) {
    acc[m][0] = z;
    acc[m][1] = z;
  }

#pragma unroll
  for (int ks = 0; ks < 8; ++ks) {
    const int kb = ks * 4 + q;
    const bf16x8 b0 = ring[ks & 3][0];
    const bf16x8 b1 = ring[ks & 3][1];
    // refill slot: 4 iterations ahead (crosses into next layer's W)
    if (ks < 4) {
      ring[ks & 3][0] = *(const bf16x8*)(wcur + (ks + 4) * 32);
      ring[ks & 3][1] = *(const bf16x8*)(wcur + 4096 + (ks + 4) * 32);
    } else if (!LAST) {
      ring[ks & 3][0] = *(const bf16x8*)(wnext + (ks - 4) * 32);
      ring[ks & 3][1] = *(const bf16x8*)(wnext + 4096 + (ks - 4) * 32);
    }
#pragma unroll
    for (int m = 0; m < 8; ++m) {
      const int row = m * 16 + r16;
      const bf16x8 a = *(const bf16x8*)(&Hs[kb * 1024 + (((row + kb) & 127) << 3)]);
      // swapped operands (verified): acc[m][nt] -> row m*16+r16,
      // cols nq*32 + nt*16 + q*4 + reg
      acc[m][0] = __builtin_amdgcn_mfma_f32_16x16x32_bf16(b0, a, acc[m][0], 0, 0, 0);
      acc[m][1] = __builtin_amdgcn_mfma_f32_16x16x32_bf16(b1, a, acc[m][1], 0, 0, 0);
    }
  }

  f32x4 bv[2];
#pragma unroll
  for (int nt = 0; nt < 2; ++nt)
    bv[nt] = *(const f32x4*)&bias_g[nq * 32 + nt * 16 + q * 4];

  if (!LAST) {
    // compute store values first (register math overlaps barrier wait)
    bf16x4 hv[8][2];
#pragma unroll
    for (int m = 0; m < 8; ++m)
#pragma unroll
      for (int nt = 0; nt < 2; ++nt) {
        const f32x4 s = acc[m][nt] + bv[nt];
        bf16x4 h;
#pragma unroll
        for (int r = 0; r < 4; ++r) h[r] = (__bf16)fmaxf(s[r], 0.f);
        hv[m][nt] = h;
      }
    __syncthreads();   // BAR1: all waves finished reading Hs -> in-place safe
#pragma unroll
    for (int m = 0; m < 8; ++m)
#pragma unroll
      for (int nt = 0; nt < 2; ++nt) {
        const int cb = nq * 32 + nt * 16 + q * 4;
        *(bf16x4*)(&Hs[hidx128(m * 16 + r16, cb)]) = hv[m][nt];
      }
    __syncthreads();   // BAR2: stores visible before next layer's reads
  } else {
    // j-sum for both i halves: rows 0-63 (m 0..3) -> i0, 64-127 (m 4..7) -> i1
#pragma unroll
    for (int h = 0; h < 2; ++h) {
#pragma unroll
      for (int nt = 0; nt < 2; ++nt) {
        const int cb = nq * 32 + nt * 16 + q * 4;
        f32x4 s;
#pragma unroll
        for (int r = 0; r < 4; ++r)
          s[r] = fmaxf(acc[h * 4 + 0][nt][r] + bv[nt][r], 0.f)
               + fmaxf(acc[h * 4 + 1][nt][r] + bv[nt][r], 0.f)
               + fmaxf(acc[h * 4 + 2][nt][r] + bv[nt][r], 0.f)
               + fmaxf(acc[h * 4 + 3][nt][r] + bv[nt][r], 0.f);
#pragma unroll
        for (int d = 1; d < 16; d <<= 1) {
#pragma unroll
          for (int r = 0; r < 4; ++r) s[r] += __shfl_xor(s[r], d, 64);
        }
        if (r16 == 0) *(f32x4*)&(h ? pr1 : pr0)[cb] = s;
      }
    }
  }
}

__global__ __launch_bounds__(512, 4) void rn_main(
    const float* __restrict__ U, const float* __restrict__ V,
    const float* __restrict__ Qb,
    const __bf16* __restrict__ W2t, const __bf16* __restrict__ W3t,
    const __bf16* __restrict__ W4t,
    const float* __restrict__ b2, const float* __restrict__ b3,
    const float* __restrict__ b4,
    float* __restrict__ part) {
  __shared__ __align__(16) __bf16 Hs[32768];   // 64 KB, in-place
  const int blk = blockIdx.x;
  const int nimg = blk >> 5, ipair = blk & 31;
  const int iobj0 = ipair * 2;
  const int t = threadIdx.x;
  const int nq = t >> 6, lane = t & 63;
  const int q = lane >> 4, r16 = lane & 15;

  // per-wave W base pointers (row = output col = nq*32 [+16] + r16, K off q*8)
  const size_t woff = (size_t)(nq * 32 + r16) * 256 + q * 8;
  const __bf16* w2 = W2t + woff;
  const __bf16* w3 = W3t + woff;
  const __bf16* w4 = W4t + woff;

  // start layer-2 B ring fill immediately (overlaps phase-0 loads/math)
  bf16x8 ring[4][2];
#pragma unroll
  for (int d = 0; d < 4; ++d) {
    ring[d][0] = *(const bf16x8*)(w2 + d * 32);
    ring[d][1] = *(const bf16x8*)(w2 + 4096 + d * 32);
  }

  // phase 0: rows 0-63 -> i0, rows 64-127 -> i1
  // h1[row][:] = relu(U[n, i(row), :] + V[n, j(row), :] + Qb[n, :])
  {
    const int c4 = t & 63;          // 4-float col group
    const int rb = t >> 6;          // 0..7 -> rows rb*16 .. rb*16+15
    const int isel = rb >> 2;       // 0 or 1 (static per thread)
    const f32x4 u4 = *(const f32x4*)&U[(size_t)(nimg * 64 + iobj0 + isel) * 256 + c4 * 4];
    const f32x4 q4 = *(const f32x4*)&Qb[(size_t)nimg * 256 + c4 * 4];
    const f32x4 uq = u4 + q4;
#pragma unroll
    for (int jj = 0; jj < 16; ++jj) {
      const int row = rb * 16 + jj;
      const int j = (rb & 3) * 16 + jj;
      const f32x4 v4 = *(const f32x4*)&V[(size_t)(nimg * 64 + j) * 256 + c4 * 4];
      bf16x4 h;
#pragma unroll
      for (int r = 0; r < 4; ++r) h[r] = (__bf16)fmaxf(uq[r] + v4[r], 0.f);
      *(bf16x4*)(&Hs[hidx128(row, c4 * 4)]) = h;
    }
  }
  __syncthreads();

  // part rows: global i-row index = nimg*64 + iobj0 (+1) = blk*2 (+1)
  float* pr0 = part + (size_t)blk * 512;
  float* pr1 = pr0 + 256;

  g_layer<false>(Hs, ring, w2, w3, b2, nq, q, r16, pr0, pr1);
  g_layer<false>(Hs, ring, w3, w4, b3, nq, q, r16, pr0, pr1);
  g_layer<true >(Hs, ring, w4, w4, b4, nq, q, r16, pr0, pr1);
}

// ---------------------------------------------------------------------------
// Kernel 3: reduce partials -> context, f-MLP (fp32), log_softmax
// ---------------------------------------------------------------------------
__global__ __launch_bounds__(256) void rn_final(
    const float* __restrict__ part,
    const float* __restrict__ f_w1, const float* __restrict__ f_b1,
    const float* __restrict__ f_w2, const float* __restrict__ f_b2,
    const float* __restrict__ f_w3, const float* __restrict__ f_b3,
    float* __restrict__ out) {
  __shared__ float ctx[256], y1[256], y2[256], sc[2];
  const int n = blockIdx.x, t = threadIdx.x;

  float s = 0.f;
  for (int i = 0; i < 64; ++i) s += part[((size_t)n * 64 + i) * 256 + t];
  ctx[t] = s * (1.0f / 4096.0f);
  __syncthreads();

  float a = f_b1[t];
  for (int k = 0; k < 256; ++k) a += ctx[k] * f_w1[k * 256 + t];
  y1[t] = fmaxf(a, 0.f);
  __syncthreads();

  float b = f_b2[t];
  for (int k = 0; k < 256; ++k) b += y1[k] * f_w2[k * 256 + t];
  y2[t] = fmaxf(b, 0.f);
  __syncthreads();

  if (t < 2) {
    float c = f_b3[t];
    for (int k = 0; k < 256; ++k) c += y2[k] * f_w3[k * 2 + t];
    sc[t] = c;
  }
  __syncthreads();

  if (t == 0) {
    const float s0 = sc[0], s1 = sc[1];
    const float mx = fmaxf(s0, s1);
    const float lse = mx + logf(expf(s0 - mx) + expf(s1 - mx));
    out[n * 2 + 0] = s0 - lse;
    out[n * 2 + 1] = s1 - lse;
  }
}

// ---------------------------------------------------------------------------
extern "C" void kernel_launch(void* const* d_in, const int* in_sizes, int n_in,
                              void* d_out, int out_size, void* d_ws, size_t ws_size,
                              hipStream_t stream) {
  const float* img  = (const float*)d_in[0];
  const float* ques = (const float*)d_in[1];
  const float* g_w1 = (const float*)d_in[2];
  const float* g_b1 = (const float*)d_in[3];
  const float* g_w2 = (const float*)d_in[4];
  const float* g_b2 = (const float*)d_in[5];
  const float* g_w3 = (const float*)d_in[6];
  const float* g_b3 = (const float*)d_in[7];
  const float* g_w4 = (const float*)d_in[8];
  const float* g_b4 = (const float*)d_in[9];
  const float* f_w1 = (const float*)d_in[10];
  const float* f_b1 = (const float*)d_in[11];
  const float* f_w2 = (const float*)d_in[12];
  const float* f_b2 = (const float*)d_in[13];
  const float* f_w3 = (const float*)d_in[14];
  const float* f_b3 = (const float*)d_in[15];
  float* out = (float*)d_out;

  char* ws = (char*)d_ws;
  float*  U    = (float*)(ws);                                 // 4 MB
  float*  V    = (float*)(ws + (size_t)4  * 1048576);          // 4 MB
  float*  part = (float*)(ws + (size_t)8  * 1048576);          // 4 MB
  float*  Qb   = (float*)(ws + (size_t)12 * 1048576);          // 64 KB
  __bf16* W2t  = (__bf16*)(ws + (size_t)12 * 1048576 + 65536); // 128 KB each
  __bf16* W3t  = W2t + 65536;
  __bf16* W4t  = W3t + 65536;

  prep_kernel<<<368, 256, 0, stream>>>(img, ques, g_w1, g_b1, g_w2, g_w3, g_w4,
                                       U, V, Qb, W2t, W3t, W4t);
  rn_main<<<2048, 512, 0, stream>>>(U, V, Qb, W2t, W3t, W4t, g_b2, g_b3, g_b4, part);
  rn_final<<<64, 256, 0, stream>>>(part, f_w1, f_b1, f_w2, f_b2, f_w3, f_b3, out);
}